// Round 3
// baseline (714.269 us; speedup 1.0000x reference)
//
#include <hip/hip_runtime.h>
#include <math.h>

#define BB 2
#define DD 8
#define HH 128
#define WW2 128
#define CC 64
#define NPT (DD*HH*WW2)        // 131072
#define NTOT (BB*NPT)          // 262144

typedef __attribute__((ext_vector_type(8))) short short8;
typedef __attribute__((ext_vector_type(4))) float f32x4;
typedef __attribute__((ext_vector_type(4))) unsigned short u16x4;
typedef unsigned short u16;

// ---- workspace layout (bytes) ----
static const size_t OFF_QT  = 0;                 // 33554432  bf16 [b][64][N] (aliased by p1 later)
static const size_t OFF_KT  = 33554432;          // 33554432  bf16 [b][64][N] (aliased by p2 later)
static const size_t OFF_V   = 67108864;          // 33554432  bf16 [b][n][64]
static const size_t OFF_PW  = 100663296;         // 24576     packed W frags
static const size_t OFF_PM  = 100687872;         // 16384     packed M frags
static const size_t OFF_G   = 100704256;         // 8192      fp32 [b][4][16][16]
static const size_t OFF_NK  = 100712448;         // 512
static const size_t OFF_NQ  = 100712960;         // 512
static const size_t OFF_FLAG= 100713472;         // 4 (pad to 512)
static const size_t OFF_CW  = 100713984;         // ~80KB fp32 canonical weights
// cw float offsets:
#define CW_WQ    0
#define CW_WK    4096
#define CW_WV    8192
#define CW_WPROJ 12288
#define CW_WPOS1 16384
#define CW_WPOS2 18112
#define CW_RESC  19840
#define CW_BPROJ 19844

__device__ __forceinline__ float bf2f(u16 u){
  unsigned int x = ((unsigned int)u) << 16;
  return __builtin_bit_cast(float, x);
}
__device__ __forceinline__ u16 f2bf(float f){
  unsigned int x = __builtin_bit_cast(unsigned int, f);
  unsigned int r = (x + 0x7fffu + ((x >> 16) & 1u)) >> 16;
  return (u16)r;
}

// ---- probe dtype of x, canonicalize small weights to fp32, zero accumulators ----
__global__ __launch_bounds__(256) void k_prep(const void* __restrict__ x,
    const void* __restrict__ Wq, const void* __restrict__ Wk, const void* __restrict__ Wv,
    const void* __restrict__ rescale, const void* __restrict__ Wproj, const void* __restrict__ bproj,
    const void* __restrict__ Wpos1, const void* __restrict__ Wpos2,
    int* __restrict__ flag, float* __restrict__ cw, float* __restrict__ gz){
  __shared__ int sflag;
  int t = threadIdx.x;
  if (t < 64){
    // bf16 data: even u16s are sane bf16 (exp in [100,130] for ~N(0,1)); fp32 data:
    // even u16 = mantissa low bits -> pseudo-uniform, ~12% pass rate.
    u16 u = ((const u16*)x)[2 * t];
    int e = (u >> 7) & 0xFF;
    int plaus = (u == 0) || (u == 0x8000u) || (e >= 100 && e <= 130);
    unsigned long long m = __ballot(plaus);
    if (t == 0){
      sflag = (__popcll(m) < 48) ? 1 : 0;   // 1 => inputs are fp32
      *flag = sflag;
    }
  }
  __syncthreads();
  int isf32 = sflag;
  auto conv = [&](const void* src, float* dst, int n){
    for (int i = t; i < n; i += 256)
      dst[i] = isf32 ? ((const float*)src)[i] : bf2f(((const u16*)src)[i]);
  };
  conv(Wq,    cw + CW_WQ,    4096);
  conv(Wk,    cw + CW_WK,    4096);
  conv(Wv,    cw + CW_WV,    4096);
  conv(Wproj, cw + CW_WPROJ, 4096);
  conv(Wpos1, cw + CW_WPOS1, 1728);
  conv(Wpos2, cw + CW_WPOS2, 1728);
  conv(rescale, cw + CW_RESC, 4);
  conv(bproj,   cw + CW_BPROJ, 64);
  for (int i = t; i < 2304; i += 256) gz[i] = 0.f;   // G + Nk2 + Nq2
}

// ---- pack [Wq|Wk|Wv] (64x192) into MFMA B-fragment order ----
__global__ __launch_bounds__(256) void kpack_w(const float* __restrict__ cw, u16* __restrict__ packW){
  int o = blockIdx.x * 256 + threadIdx.x;      // 48*256 = 12288
  int f = o >> 9, l = (o >> 3) & 63, j = o & 7;
  int tt = f >> 1, s = f & 1;
  int k = s * 32 + (l >> 4) * 8 + j;
  int n = tt * 16 + (l & 15);
  float val;
  if (n < 64)       val = cw[CW_WQ    + k * 64 + n];
  else if (n < 128) val = cw[CW_WK    + k * 64 + (n - 64)];
  else              val = cw[CW_WV    + k * 64 + (n - 128)];
  packW[o] = f2bf(val);
}

__device__ __forceinline__ short8 ld8_adapt(const void* p, size_t idx, int isf32){
  if (!isf32) return *(const short8*)((const u16*)p + idx);
  const float4* f = (const float4*)((const float*)p + idx);
  float4 u = f[0], v2 = f[1];
  short8 r;
  r[0] = (short)f2bf(u.x);  r[1] = (short)f2bf(u.y);
  r[2] = (short)f2bf(u.z);  r[3] = (short)f2bf(u.w);
  r[4] = (short)f2bf(v2.x); r[5] = (short)f2bf(v2.y);
  r[6] = (short)f2bf(v2.z); r[7] = (short)f2bf(v2.w);
  return r;
}

// ---- QKV GEMM: x[262144x64] @ W[64x192] ----
__global__ __launch_bounds__(256) void k_qkv(const void* __restrict__ x, const int* __restrict__ flag,
                                             const u16* __restrict__ packW,
                                             u16* __restrict__ qT, u16* __restrict__ kT,
                                             u16* __restrict__ v){
  int isf32 = *flag;
  int wave = threadIdx.x >> 6, lane = threadIdx.x & 63;
  int m = lane & 15, quad = lane >> 4;
  int p0 = blockIdx.x * 64 + wave * 16;
  size_t rowbase = (size_t)(p0 + m) * 64;
  short8 a0 = ld8_adapt(x, rowbase + quad * 8, isf32);        // k = quad*8+j
  short8 a1 = ld8_adapt(x, rowbase + 32 + quad * 8, isf32);   // k = 32+quad*8+j
  const short8* bw = (const short8*)packW;
  f32x4 acc[12];
#pragma unroll
  for (int t = 0; t < 12; t++) acc[t] = (f32x4)(0.f);
#pragma unroll
  for (int t = 0; t < 12; t++){
    short8 b0 = bw[(t * 2 + 0) * 64 + lane];
    short8 b1 = bw[(t * 2 + 1) * 64 + lane];
    acc[t] = __builtin_amdgcn_mfma_f32_16x16x32_bf16(a0, b0, acc[t], 0, 0, 0);
    acc[t] = __builtin_amdgcn_mfma_f32_16x16x32_bf16(a1, b1, acc[t], 0, 0, 0);
  }
  int b = p0 >> 17;                 // NPT = 2^17
  int nloc = p0 & (NPT - 1);
  // q,k -> transposed [ch][n] (C/D layout: point=quad*4+r, ch=t*16+m)
#pragma unroll
  for (int t = 0; t < 4; t++){
    int ch = t * 16 + m;
    u16x4 pk;
#pragma unroll
    for (int r = 0; r < 4; r++) pk[r] = f2bf(acc[t][r]);
    *(u16x4*)(qT + ((size_t)(b * 64 + ch)) * NPT + nloc + quad * 4) = pk;
  }
#pragma unroll
  for (int t = 4; t < 8; t++){
    int ch = (t - 4) * 16 + m;
    u16x4 pk;
#pragma unroll
    for (int r = 0; r < 4; r++) pk[r] = f2bf(acc[t][r]);
    *(u16x4*)(kT + ((size_t)(b * 64 + ch)) * NPT + nloc + quad * 4) = pk;
  }
  // v -> row-major [n][ch]
#pragma unroll
  for (int t = 8; t < 12; t++){
    int ch = (t - 8) * 16 + m;
#pragma unroll
    for (int r = 0; r < 4; r++){
      size_t p = (size_t)p0 + quad * 4 + r;
      v[p * 64 + ch] = f2bf(acc[t][r]);
    }
  }
}

// ---- Gram matrices + norms via MFMA ----
__global__ __launch_bounds__(256) void k_gram(const u16* __restrict__ qT, const u16* __restrict__ kT,
                                              float* __restrict__ G, float* __restrict__ Nk2,
                                              float* __restrict__ Nq2){
  int wave = threadIdx.x >> 6, lane = threadIdx.x & 63;
  int m = lane & 15, quad = lane >> 4;
  int chunk = blockIdx.x;            // 16
  int bh = blockIdx.y;               // 8
  int b = bh >> 2, h = bh & 3;
  const u16* rowK = kT + ((size_t)(b * 64 + h * 16 + m)) * NPT;
  const u16* rowQ = qT + ((size_t)(b * 64 + h * 16 + m)) * NPT;
  int base = chunk * (NPT / 16) + wave * (NPT / 64);
  f32x4 aG = (f32x4)(0.f), aKK = (f32x4)(0.f), aQQ = (f32x4)(0.f);
  for (int s2 = 0; s2 < 64; s2++){
    int p = base + s2 * 32 + quad * 8;
    short8 ka = *(const short8*)(rowK + p);
    short8 qa = *(const short8*)(rowQ + p);
    aG  = __builtin_amdgcn_mfma_f32_16x16x32_bf16(ka, qa, aG, 0, 0, 0);
    aKK = __builtin_amdgcn_mfma_f32_16x16x32_bf16(ka, ka, aKK, 0, 0, 0);
    aQQ = __builtin_amdgcn_mfma_f32_16x16x32_bf16(qa, qa, aQQ, 0, 0, 0);
  }
  float* Gb = G + (size_t)((b * 4 + h) * 16) * 16;
#pragma unroll
  for (int r = 0; r < 4; r++){
    int d = quad * 4 + r, e = m;
    atomicAdd(&Gb[d * 16 + e], aG[r]);
    if (d == e){
      atomicAdd(&Nk2[b * 64 + h * 16 + d], aKK[r]);
      atomicAdd(&Nq2[b * 64 + h * 16 + d], aQQ[r]);
    }
  }
}

// ---- softmax + fold attn into Wproj, pack M into B-frag order ----
__global__ __launch_bounds__(256) void k_attn(const float* __restrict__ G, const float* __restrict__ Nk2,
                                              const float* __restrict__ Nq2, const float* __restrict__ cw,
                                              u16* __restrict__ packM){
  __shared__ float sA[4][16][16];
  __shared__ float sM[64][64];
  __shared__ float sWp[64][64];
  const float* Wprojf = cw + CW_WPROJ;
  const float* rescf  = cw + CW_RESC;
  int b = blockIdx.x;
  int t = threadIdx.x;
  for (int i = t; i < 4096; i += 256) sWp[i >> 6][i & 63] = Wprojf[i];
  if (t < 64){
    int h = t >> 4, d = t & 15;
    float nk = fmaxf(sqrtf(Nk2[b * 64 + h * 16 + d]), 1e-12f);
    float rs = rescf[h];
    float lg[16]; float mx = -1e30f;
#pragma unroll
    for (int e = 0; e < 16; e++){
      float nq = fmaxf(sqrtf(Nq2[b * 64 + h * 16 + e]), 1e-12f);
      float L = G[((size_t)(b * 4 + h) * 16 + d) * 16 + e] / (nk * nq) * rs;
      lg[e] = L; mx = fmaxf(mx, L);
    }
    float sum = 0.f;
#pragma unroll
    for (int e = 0; e < 16; e++){ lg[e] = expf(lg[e] - mx); sum += lg[e]; }
    float inv = 1.f / sum;
#pragma unroll
    for (int e = 0; e < 16; e++) sA[h][d][e] = lg[e] * inv;
  }
  __syncthreads();
  // M[he][c] = sum_d attn[h][d][e] * Wproj[h*16+d][c]
  for (int i = t; i < 4096; i += 256){
    int he = i >> 6, c = i & 63;
    int h = he >> 4, e = he & 15;
    float acc = 0.f;
#pragma unroll
    for (int d = 0; d < 16; d++) acc += sA[h][d][e] * sWp[h * 16 + d][c];
    sM[he][c] = acc;
  }
  __syncthreads();
  for (int i = t; i < 4096; i += 256){
    int f = i >> 9, l = (i >> 3) & 63, j = i & 7;
    int t4 = f >> 1, s = f & 1;
    int k = s * 32 + (l >> 4) * 8 + j;
    int n = t4 * 16 + (l & 15);
    packM[b * 4096 + i] = f2bf(sM[k][n]);
  }
}

// ---- depthwise 3x3x3 conv (SAME), optional exact GELU, h-rolling registers ----
template <bool GELU>
__global__ __launch_bounds__(256) void k_dwconv(const u16* __restrict__ src, const float* __restrict__ wpos,
                                                u16* __restrict__ dst){
  int c = threadIdx.x & 63, wq = threadIdx.x >> 6;
  int wt = blockIdx.x;              // 32 tiles of 4 w
  int d0 = blockIdx.y;              // 0..7
  int b = blockIdx.z;               // 0..1
  int w = wt * 4 + wq;
  float wgt[27];
#pragma unroll
  for (int i = 0; i < 27; i++) wgt[i] = wpos[c * 27 + i];
  const size_t srcB = (size_t)b * NPT * 64;
  float r[3][3][3];   // [kh][kd][kw]
  auto load_row = [&](int yy, float (&slot)[3][3]){
#pragma unroll
    for (int kd = 0; kd < 3; kd++){
      int z = d0 - 1 + kd;
#pragma unroll
      for (int kw = 0; kw < 3; kw++){
        int xx = w - 1 + kw;
        float val = 0.f;
        if (yy >= 0 && yy < HH && z >= 0 && z < DD && xx >= 0 && xx < WW2)
          val = bf2f(src[srcB + (((size_t)z * HH + yy) * WW2 + xx) * 64 + c]);
        slot[kd][kw] = val;
      }
    }
  };
  load_row(-1, r[0]);
  load_row(0,  r[1]);
  load_row(1,  r[2]);
  for (int y = 0; y < HH; y++){
    float acc = 0.f;
#pragma unroll
    for (int kh = 0; kh < 3; kh++)
#pragma unroll
      for (int kd = 0; kd < 3; kd++)
#pragma unroll
        for (int kw = 0; kw < 3; kw++)
          acc = fmaf(r[kh][kd][kw], wgt[kd * 9 + kh * 3 + kw], acc);
    if (GELU) acc = 0.5f * acc * (1.f + erff(acc * 0.70710678118654752f));
    dst[srcB + (((size_t)d0 * HH + y) * WW2 + w) * 64 + c] = f2bf(acc);
#pragma unroll
    for (int kd = 0; kd < 3; kd++)
#pragma unroll
      for (int kw = 0; kw < 3; kw++){
        r[0][kd][kw] = r[1][kd][kw];
        r[1][kd][kw] = r[2][kd][kw];
      }
    load_row(y + 2, r[2]);
  }
}

// ---- final: v @ M + bproj + conv2 output -> fp32 out ----
__global__ __launch_bounds__(256) void k_final(const u16* __restrict__ v, const u16* __restrict__ packM,
                                               const float* __restrict__ bprojf, const u16* __restrict__ p2,
                                               float* __restrict__ out){
  int wave = threadIdx.x >> 6, lane = threadIdx.x & 63;
  int m = lane & 15, quad = lane >> 4;
  int p0 = blockIdx.x * 64 + wave * 16;
  int b = p0 >> 17;
  const short8* va = (const short8*)(v + (size_t)(p0 + m) * 64 + quad * 8);
  short8 a0 = va[0], a1 = va[4];
  const short8* bm = (const short8*)(packM + (size_t)b * 4096);
  f32x4 acc[4];
#pragma unroll
  for (int t = 0; t < 4; t++) acc[t] = (f32x4)(0.f);
#pragma unroll
  for (int t = 0; t < 4; t++){
    short8 b0 = bm[(t * 2 + 0) * 64 + lane];
    short8 b1 = bm[(t * 2 + 1) * 64 + lane];
    acc[t] = __builtin_amdgcn_mfma_f32_16x16x32_bf16(a0, b0, acc[t], 0, 0, 0);
    acc[t] = __builtin_amdgcn_mfma_f32_16x16x32_bf16(a1, b1, acc[t], 0, 0, 0);
  }
#pragma unroll
  for (int t = 0; t < 4; t++){
    int c = t * 16 + m;
    float bias = bprojf[c];
#pragma unroll
    for (int r = 0; r < 4; r++){
      size_t p = (size_t)p0 + quad * 4 + r;
      out[p * 64 + c] = acc[t][r] + bias + bf2f(p2[p * 64 + c]);
    }
  }
}

extern "C" void kernel_launch(void* const* d_in, const int* in_sizes, int n_in,
                              void* d_out, int out_size, void* d_ws, size_t ws_size,
                              hipStream_t stream){
  (void)in_sizes; (void)n_in; (void)out_size; (void)ws_size;
  const void* x      = d_in[0];
  const void* Wq     = d_in[1];
  const void* Wk     = d_in[2];
  const void* Wv     = d_in[3];
  const void* rescale= d_in[4];
  const void* Wproj  = d_in[5];
  const void* bproj  = d_in[6];
  const void* Wpos1  = d_in[7];
  const void* Wpos2  = d_in[8];

  char* ws = (char*)d_ws;
  u16* qT    = (u16*)(ws + OFF_QT);
  u16* kT    = (u16*)(ws + OFF_KT);
  u16* vv    = (u16*)(ws + OFF_V);
  u16* packW = (u16*)(ws + OFF_PW);
  u16* packM = (u16*)(ws + OFF_PM);
  float* G   = (float*)(ws + OFF_G);
  float* Nk2 = (float*)(ws + OFF_NK);
  float* Nq2 = (float*)(ws + OFF_NQ);
  int* flag  = (int*)(ws + OFF_FLAG);
  float* cw  = (float*)(ws + OFF_CW);
  u16* p1g   = (u16*)(ws + OFF_QT);   // alias: safe after k_gram consumed qT
  u16* p2    = (u16*)(ws + OFF_KT);   // alias: safe after k_gram consumed kT
  float* out = (float*)d_out;

  k_prep<<<1, 256, 0, stream>>>(x, Wq, Wk, Wv, rescale, Wproj, bproj, Wpos1, Wpos2, flag, cw, G);
  kpack_w<<<48, 256, 0, stream>>>(cw, packW);
  k_qkv<<<NTOT / 64, 256, 0, stream>>>(x, flag, packW, qT, kT, vv);
  k_gram<<<dim3(16, 8), 256, 0, stream>>>(qT, kT, G, Nk2, Nq2);
  k_attn<<<2, 256, 0, stream>>>(G, Nk2, Nq2, cw, packM);
  k_dwconv<true><<<dim3(32, 8, 2), 256, 0, stream>>>(vv, cw + CW_WPOS1, p1g);
  k_dwconv<false><<<dim3(32, 8, 2), 256, 0, stream>>>(p1g, cw + CW_WPOS2, p2);
  k_final<<<NTOT / 64, 256, 0, stream>>>(vv, packM, cw + CW_BPROJ, p2, out);
}

// Round 4
// 484.665 us; speedup vs baseline: 1.4737x; 1.4737x over previous
//
#include <hip/hip_runtime.h>
#include <math.h>

#define BB 2
#define DD 8
#define HH 128
#define WW2 128
#define CC 64
#define NPT (DD*HH*WW2)        // 131072
#define NTOT (BB*NPT)          // 262144

typedef __attribute__((ext_vector_type(8))) short short8;
typedef __attribute__((ext_vector_type(4))) float f32x4;
typedef __attribute__((ext_vector_type(4))) unsigned short u16x4;
typedef unsigned short u16;

// ---- workspace layout (bytes) ----
static const size_t OFF_QT  = 0;                 // 33554432  bf16 [b][64][N] (aliased by p1 later)
static const size_t OFF_KT  = 33554432;          // 33554432  bf16 [b][64][N] (aliased by p2 later)
static const size_t OFF_V   = 67108864;          // 33554432  bf16 [b][n][64]
static const size_t OFF_PW  = 100663296;         // 24576     packed W frags
static const size_t OFF_PM  = 100687872;         // 16384     packed M frags
static const size_t OFF_G   = 100704256;         // 8192      fp32 [b][4][16][16]
static const size_t OFF_NK  = 100712448;         // 512
static const size_t OFF_NQ  = 100712960;         // 512
static const size_t OFF_FLAG= 100713472;         // 4 (pad to 512)
static const size_t OFF_CW  = 100713984;         // ~80KB fp32 canonical weights
// cw float offsets:
#define CW_WQ    0
#define CW_WK    4096
#define CW_WV    8192
#define CW_WPROJ 12288
#define CW_WPOS1 16384
#define CW_WPOS2 18112
#define CW_RESC  19840
#define CW_BPROJ 19844

__device__ __forceinline__ float bf2f(u16 u){
  unsigned int x = ((unsigned int)u) << 16;
  return __builtin_bit_cast(float, x);
}
__device__ __forceinline__ u16 f2bf(float f){
  unsigned int x = __builtin_bit_cast(unsigned int, f);
  unsigned int r = (x + 0x7fffu + ((x >> 16) & 1u)) >> 16;
  return (u16)r;
}

// ---- probe dtype of x, canonicalize small weights to fp32, zero accumulators ----
__global__ __launch_bounds__(256) void k_prep(const void* __restrict__ x,
    const void* __restrict__ Wq, const void* __restrict__ Wk, const void* __restrict__ Wv,
    const void* __restrict__ rescale, const void* __restrict__ Wproj, const void* __restrict__ bproj,
    const void* __restrict__ Wpos1, const void* __restrict__ Wpos2,
    int* __restrict__ flag, float* __restrict__ cw, float* __restrict__ gz){
  __shared__ int sflag;
  int t = threadIdx.x;
  if (t < 64){
    u16 u = ((const u16*)x)[2 * t];
    int e = (u >> 7) & 0xFF;
    int plaus = (u == 0) || (u == 0x8000u) || (e >= 100 && e <= 130);
    unsigned long long m = __ballot(plaus);
    if (t == 0){
      sflag = (__popcll(m) < 48) ? 1 : 0;   // 1 => inputs are fp32
      *flag = sflag;
    }
  }
  __syncthreads();
  int isf32 = sflag;
  auto conv = [&](const void* src, float* dst, int n){
    for (int i = t; i < n; i += 256)
      dst[i] = isf32 ? ((const float*)src)[i] : bf2f(((const u16*)src)[i]);
  };
  conv(Wq,    cw + CW_WQ,    4096);
  conv(Wk,    cw + CW_WK,    4096);
  conv(Wv,    cw + CW_WV,    4096);
  conv(Wproj, cw + CW_WPROJ, 4096);
  conv(Wpos1, cw + CW_WPOS1, 1728);
  conv(Wpos2, cw + CW_WPOS2, 1728);
  conv(rescale, cw + CW_RESC, 4);
  conv(bproj,   cw + CW_BPROJ, 64);
  for (int i = t; i < 2304; i += 256) gz[i] = 0.f;   // G + Nk2 + Nq2
}

// ---- pack [Wq|Wk|Wv] (64x192) into MFMA B-fragment order ----
__global__ __launch_bounds__(256) void kpack_w(const float* __restrict__ cw, u16* __restrict__ packW){
  int o = blockIdx.x * 256 + threadIdx.x;      // 48*256 = 12288
  int f = o >> 9, l = (o >> 3) & 63, j = o & 7;
  int tt = f >> 1, s = f & 1;
  int k = s * 32 + (l >> 4) * 8 + j;
  int n = tt * 16 + (l & 15);
  float val;
  if (n < 64)       val = cw[CW_WQ    + k * 64 + n];
  else if (n < 128) val = cw[CW_WK    + k * 64 + (n - 64)];
  else              val = cw[CW_WV    + k * 64 + (n - 128)];
  packW[o] = f2bf(val);
}

__device__ __forceinline__ short8 ld8_adapt(const void* p, size_t idx, int isf32){
  if (!isf32) return *(const short8*)((const u16*)p + idx);
  const float4* f = (const float4*)((const float*)p + idx);
  float4 u = f[0], v2 = f[1];
  short8 r;
  r[0] = (short)f2bf(u.x);  r[1] = (short)f2bf(u.y);
  r[2] = (short)f2bf(u.z);  r[3] = (short)f2bf(u.w);
  r[4] = (short)f2bf(v2.x); r[5] = (short)f2bf(v2.y);
  r[6] = (short)f2bf(v2.z); r[7] = (short)f2bf(v2.w);
  return r;
}

// ---- QKV GEMM: x[262144x64] @ W[64x192] ----
__global__ __launch_bounds__(256) void k_qkv(const void* __restrict__ x, const int* __restrict__ flag,
                                             const u16* __restrict__ packW,
                                             u16* __restrict__ qT, u16* __restrict__ kT,
                                             u16* __restrict__ v){
  int isf32 = *flag;
  int wave = threadIdx.x >> 6, lane = threadIdx.x & 63;
  int m = lane & 15, quad = lane >> 4;
  int p0 = blockIdx.x * 64 + wave * 16;
  size_t rowbase = (size_t)(p0 + m) * 64;
  short8 a0 = ld8_adapt(x, rowbase + quad * 8, isf32);        // k = quad*8+j
  short8 a1 = ld8_adapt(x, rowbase + 32 + quad * 8, isf32);   // k = 32+quad*8+j
  const short8* bw = (const short8*)packW;
  f32x4 acc[12];
#pragma unroll
  for (int t = 0; t < 12; t++) acc[t] = (f32x4)(0.f);
#pragma unroll
  for (int t = 0; t < 12; t++){
    short8 b0 = bw[(t * 2 + 0) * 64 + lane];
    short8 b1 = bw[(t * 2 + 1) * 64 + lane];
    acc[t] = __builtin_amdgcn_mfma_f32_16x16x32_bf16(a0, b0, acc[t], 0, 0, 0);
    acc[t] = __builtin_amdgcn_mfma_f32_16x16x32_bf16(a1, b1, acc[t], 0, 0, 0);
  }
  int b = p0 >> 17;                 // NPT = 2^17
  int nloc = p0 & (NPT - 1);
  // q,k -> transposed [ch][n] (C/D layout: point=quad*4+r, ch=t*16+m)
#pragma unroll
  for (int t = 0; t < 4; t++){
    int ch = t * 16 + m;
    u16x4 pk;
#pragma unroll
    for (int r = 0; r < 4; r++) pk[r] = f2bf(acc[t][r]);
    *(u16x4*)(qT + ((size_t)(b * 64 + ch)) * NPT + nloc + quad * 4) = pk;
  }
#pragma unroll
  for (int t = 4; t < 8; t++){
    int ch = (t - 4) * 16 + m;
    u16x4 pk;
#pragma unroll
    for (int r = 0; r < 4; r++) pk[r] = f2bf(acc[t][r]);
    *(u16x4*)(kT + ((size_t)(b * 64 + ch)) * NPT + nloc + quad * 4) = pk;
  }
  // v -> row-major [n][ch]
#pragma unroll
  for (int t = 8; t < 12; t++){
    int ch = (t - 8) * 16 + m;
#pragma unroll
    for (int r = 0; r < 4; r++){
      size_t p = (size_t)p0 + quad * 4 + r;
      v[p * 64 + ch] = f2bf(acc[t][r]);
    }
  }
}

// ---- Gram matrices + norms via MFMA (64 chunks for occupancy) ----
__global__ __launch_bounds__(256) void k_gram(const u16* __restrict__ qT, const u16* __restrict__ kT,
                                              float* __restrict__ G, float* __restrict__ Nk2,
                                              float* __restrict__ Nq2){
  int wave = threadIdx.x >> 6, lane = threadIdx.x & 63;
  int m = lane & 15, quad = lane >> 4;
  int chunk = blockIdx.x;            // 64
  int bh = blockIdx.y;               // 8
  int b = bh >> 2, h = bh & 3;
  const u16* rowK = kT + ((size_t)(b * 64 + h * 16 + m)) * NPT;
  const u16* rowQ = qT + ((size_t)(b * 64 + h * 16 + m)) * NPT;
  int base = chunk * (NPT / 64) + wave * (NPT / 256);
  f32x4 aG = (f32x4)(0.f), aKK = (f32x4)(0.f), aQQ = (f32x4)(0.f);
  for (int s2 = 0; s2 < 16; s2++){
    int p = base + s2 * 32 + quad * 8;
    short8 ka = *(const short8*)(rowK + p);
    short8 qa = *(const short8*)(rowQ + p);
    aG  = __builtin_amdgcn_mfma_f32_16x16x32_bf16(ka, qa, aG, 0, 0, 0);
    aKK = __builtin_amdgcn_mfma_f32_16x16x32_bf16(ka, ka, aKK, 0, 0, 0);
    aQQ = __builtin_amdgcn_mfma_f32_16x16x32_bf16(qa, qa, aQQ, 0, 0, 0);
  }
  float* Gb = G + (size_t)((b * 4 + h) * 16) * 16;
#pragma unroll
  for (int r = 0; r < 4; r++){
    int d = quad * 4 + r, e = m;
    atomicAdd(&Gb[d * 16 + e], aG[r]);
    if (d == e){
      atomicAdd(&Nk2[b * 64 + h * 16 + d], aKK[r]);
      atomicAdd(&Nq2[b * 64 + h * 16 + d], aQQ[r]);
    }
  }
}

// ---- softmax + fold attn into Wproj, pack M into B-frag order ----
__global__ __launch_bounds__(256) void k_attn(const float* __restrict__ G, const float* __restrict__ Nk2,
                                              const float* __restrict__ Nq2, const float* __restrict__ cw,
                                              u16* __restrict__ packM){
  __shared__ float sA[4][16][16];
  __shared__ float sM[64][64];
  __shared__ float sWp[64][64];
  const float* Wprojf = cw + CW_WPROJ;
  const float* rescf  = cw + CW_RESC;
  int b = blockIdx.x;
  int t = threadIdx.x;
  for (int i = t; i < 4096; i += 256) sWp[i >> 6][i & 63] = Wprojf[i];
  if (t < 64){
    int h = t >> 4, d = t & 15;
    float nk = fmaxf(sqrtf(Nk2[b * 64 + h * 16 + d]), 1e-12f);
    float rs = rescf[h];
    float lg[16]; float mx = -1e30f;
#pragma unroll
    for (int e = 0; e < 16; e++){
      float nq = fmaxf(sqrtf(Nq2[b * 64 + h * 16 + e]), 1e-12f);
      float L = G[((size_t)(b * 4 + h) * 16 + d) * 16 + e] / (nk * nq) * rs;
      lg[e] = L; mx = fmaxf(mx, L);
    }
    float sum = 0.f;
#pragma unroll
    for (int e = 0; e < 16; e++){ lg[e] = expf(lg[e] - mx); sum += lg[e]; }
    float inv = 1.f / sum;
#pragma unroll
    for (int e = 0; e < 16; e++) sA[h][d][e] = lg[e] * inv;
  }
  __syncthreads();
  // M[he][c] = sum_d attn[h][d][e] * Wproj[h*16+d][c]
  for (int i = t; i < 4096; i += 256){
    int he = i >> 6, c = i & 63;
    int h = he >> 4, e = he & 15;
    float acc = 0.f;
#pragma unroll
    for (int d = 0; d < 16; d++) acc += sA[h][d][e] * sWp[h * 16 + d][c];
    sM[he][c] = acc;
  }
  __syncthreads();
  for (int i = t; i < 4096; i += 256){
    int f = i >> 9, l = (i >> 3) & 63, j = i & 7;
    int t4 = f >> 1, s = f & 1;
    int k = s * 32 + (l >> 4) * 8 + j;
    int n = t4 * 16 + (l & 15);
    packM[b * 4096 + i] = f2bf(sM[k][n]);
  }
}

// ---- depthwise 3x3x3 conv (SAME), y-tiled for occupancy, rolling registers ----
#define YTILE 16
template <bool GELU>
__global__ __launch_bounds__(256) void k_dwconv(const u16* __restrict__ src, const float* __restrict__ wpos,
                                                u16* __restrict__ dst){
  int c = threadIdx.x & 63, wq = threadIdx.x >> 6;
  int wt = blockIdx.x;              // 32 tiles of 4 w
  int zy = blockIdx.y;              // z*8 + ytile
  int d0 = zy >> 3;
  int y0 = (zy & 7) * YTILE;
  int b = blockIdx.z;               // 0..1
  int w = wt * 4 + wq;
  float wgt[27];
#pragma unroll
  for (int i = 0; i < 27; i++) wgt[i] = wpos[c * 27 + i];
  const size_t srcB = (size_t)b * NPT * 64;
  float r[3][3][3];   // [kh][kd][kw]
  auto load_row = [&](int yy, float (&slot)[3][3]){
#pragma unroll
    for (int kd = 0; kd < 3; kd++){
      int z = d0 - 1 + kd;
#pragma unroll
      for (int kw = 0; kw < 3; kw++){
        int xx = w - 1 + kw;
        float val = 0.f;
        if (yy >= 0 && yy < HH && z >= 0 && z < DD && xx >= 0 && xx < WW2)
          val = bf2f(src[srcB + (((size_t)z * HH + yy) * WW2 + xx) * 64 + c]);
        slot[kd][kw] = val;
      }
    }
  };
  load_row(y0 - 1, r[0]);
  load_row(y0,     r[1]);
  load_row(y0 + 1, r[2]);
  for (int y = y0; y < y0 + YTILE; y++){
    float acc = 0.f;
#pragma unroll
    for (int kh = 0; kh < 3; kh++)
#pragma unroll
      for (int kd = 0; kd < 3; kd++)
#pragma unroll
        for (int kw = 0; kw < 3; kw++)
          acc = fmaf(r[kh][kd][kw], wgt[kd * 9 + kh * 3 + kw], acc);
    if (GELU) acc = 0.5f * acc * (1.f + erff(acc * 0.70710678118654752f));
    dst[srcB + (((size_t)d0 * HH + y) * WW2 + w) * 64 + c] = f2bf(acc);
#pragma unroll
    for (int kd = 0; kd < 3; kd++)
#pragma unroll
      for (int kw = 0; kw < 3; kw++){
        r[0][kd][kw] = r[1][kd][kw];
        r[1][kd][kw] = r[2][kd][kw];
      }
    load_row(y + 2, r[2]);
  }
}

// ---- final: v @ M + bproj + conv2 output -> fp32 out ----
__global__ __launch_bounds__(256) void k_final(const u16* __restrict__ v, const u16* __restrict__ packM,
                                               const float* __restrict__ bprojf, const u16* __restrict__ p2,
                                               float* __restrict__ out){
  int wave = threadIdx.x >> 6, lane = threadIdx.x & 63;
  int m = lane & 15, quad = lane >> 4;
  int p0 = blockIdx.x * 64 + wave * 16;
  int b = p0 >> 17;
  const short8* va = (const short8*)(v + (size_t)(p0 + m) * 64 + quad * 8);
  short8 a0 = va[0], a1 = va[4];
  const short8* bm = (const short8*)(packM + (size_t)b * 4096);
  f32x4 acc[4];
#pragma unroll
  for (int t = 0; t < 4; t++) acc[t] = (f32x4)(0.f);
#pragma unroll
  for (int t = 0; t < 4; t++){
    short8 b0 = bm[(t * 2 + 0) * 64 + lane];
    short8 b1 = bm[(t * 2 + 1) * 64 + lane];
    acc[t] = __builtin_amdgcn_mfma_f32_16x16x32_bf16(a0, b0, acc[t], 0, 0, 0);
    acc[t] = __builtin_amdgcn_mfma_f32_16x16x32_bf16(a1, b1, acc[t], 0, 0, 0);
  }
#pragma unroll
  for (int t = 0; t < 4; t++){
    int c = t * 16 + m;
    float bias = bprojf[c];
#pragma unroll
    for (int r = 0; r < 4; r++){
      size_t p = (size_t)p0 + quad * 4 + r;
      out[p * 64 + c] = acc[t][r] + bias + bf2f(p2[p * 64 + c]);
    }
  }
}

extern "C" void kernel_launch(void* const* d_in, const int* in_sizes, int n_in,
                              void* d_out, int out_size, void* d_ws, size_t ws_size,
                              hipStream_t stream){
  (void)in_sizes; (void)n_in; (void)out_size; (void)ws_size;
  const void* x      = d_in[0];
  const void* Wq     = d_in[1];
  const void* Wk     = d_in[2];
  const void* Wv     = d_in[3];
  const void* rescale= d_in[4];
  const void* Wproj  = d_in[5];
  const void* bproj  = d_in[6];
  const void* Wpos1  = d_in[7];
  const void* Wpos2  = d_in[8];

  char* ws = (char*)d_ws;
  u16* qT    = (u16*)(ws + OFF_QT);
  u16* kT    = (u16*)(ws + OFF_KT);
  u16* vv    = (u16*)(ws + OFF_V);
  u16* packW = (u16*)(ws + OFF_PW);
  u16* packM = (u16*)(ws + OFF_PM);
  float* G   = (float*)(ws + OFF_G);
  float* Nk2 = (float*)(ws + OFF_NK);
  float* Nq2 = (float*)(ws + OFF_NQ);
  int* flag  = (int*)(ws + OFF_FLAG);
  float* cw  = (float*)(ws + OFF_CW);
  u16* p1g   = (u16*)(ws + OFF_QT);   // alias: safe after k_gram consumed qT
  u16* p2    = (u16*)(ws + OFF_KT);   // alias: safe after k_gram consumed kT
  float* out = (float*)d_out;

  k_prep<<<1, 256, 0, stream>>>(x, Wq, Wk, Wv, rescale, Wproj, bproj, Wpos1, Wpos2, flag, cw, G);
  kpack_w<<<48, 256, 0, stream>>>(cw, packW);
  k_qkv<<<NTOT / 64, 256, 0, stream>>>(x, flag, packW, qT, kT, vv);
  k_gram<<<dim3(64, 8), 256, 0, stream>>>(qT, kT, G, Nk2, Nq2);
  k_attn<<<2, 256, 0, stream>>>(G, Nk2, Nq2, cw, packM);
  k_dwconv<true><<<dim3(32, 64, 2), 256, 0, stream>>>(vv, cw + CW_WPOS1, p1g);
  k_dwconv<false><<<dim3(32, 64, 2), 256, 0, stream>>>(p1g, cw + CW_WPOS2, p2);
  k_final<<<NTOT / 64, 256, 0, stream>>>(vv, packM, cw + CW_BPROJ, p2, out);
}

// Round 5
// 327.727 us; speedup vs baseline: 2.1795x; 1.4789x over previous
//
#include <hip/hip_runtime.h>
#include <math.h>

#define DD 8
#define HH 128
#define WW2 128
#define NPT 131072
#define NTOT 262144
#define NBK 32

typedef __attribute__((ext_vector_type(8))) short short8;
typedef __attribute__((ext_vector_type(4))) float f32x4;
typedef __attribute__((ext_vector_type(4))) unsigned short u16x4;
typedef __attribute__((ext_vector_type(8))) unsigned short u16x8;
typedef unsigned short u16;

// ---- workspace layout (bytes) ----
// Three 33.5MB big buffers; G/N partial buckets alias the p1 region (consumed
// by k_attn BEFORE conv1 overwrites it).
static const size_t OFF_P1  = 0;          // bf16 p1T [b][64][NPT]
static const size_t OFF_P2  = 33554432;   // bf16 p2T [b][64][NPT]
static const size_t OFF_V   = 67108864;   // bf16 vT  [b][64][NPT]
static const size_t OFF_PW  = 100663296;  // 24576 packed W frags
static const size_t OFF_PM  = 100687872;  // 16384 packed M frags
static const size_t OFF_FLAG= 100704256;  // 4
static const size_t OFF_CW  = 100704768;  // 7620 floats canonical weights
// float offsets inside the partial region (base = ws + OFF_P1):
#define GP_F    0        // [NBK][2][4][16][16] = 65536 floats
#define NKP_F   65536    // [NBK][2][64] = 4096 floats
#define NQP_F   69632    // [NBK][2][64] = 4096 floats
#define NPART_TOT 73728
// cw float offsets:
#define CW_WPROJ 0
#define CW_WPOS1 4096
#define CW_WPOS2 5824
#define CW_RESC  7552
#define CW_BPROJ 7556

__device__ __forceinline__ float bf2f(u16 u){
  unsigned int x = ((unsigned int)u) << 16;
  return __builtin_bit_cast(float, x);
}
__device__ __forceinline__ u16 f2bf(float f){
  unsigned int x = __builtin_bit_cast(unsigned int, f);
  unsigned int r = (x + 0x7fffu + ((x >> 16) & 1u)) >> 16;
  return (u16)r;
}

// ---- probe dtype, canonicalize small weights, zero partial buckets ----
__global__ __launch_bounds__(256) void k_prep(const void* __restrict__ x,
    const void* __restrict__ Wproj, const void* __restrict__ rescale,
    const void* __restrict__ bproj, const void* __restrict__ Wpos1,
    const void* __restrict__ Wpos2,
    int* __restrict__ flag, float* __restrict__ cw, float* __restrict__ gpart){
  __shared__ int sflag;
  int t = threadIdx.x, blk = blockIdx.x;
  for (int i = blk * 2304 + t; i < (blk + 1) * 2304 && i < NPART_TOT; i += 256)
    gpart[i] = 0.f;                       // 32 * 2304 = 73728 exact
  if (blk != 0) return;
  if (t < 64){
    // bf16 data: even u16s have sane exponents; fp32 data: even u16 = mantissa bits
    u16 u = ((const u16*)x)[2 * t];
    int e = (u >> 7) & 0xFF;
    int plaus = (u == 0) || (u == 0x8000u) || (e >= 100 && e <= 130);
    unsigned long long m = __ballot(plaus);
    if (t == 0){
      sflag = (__popcll(m) < 48) ? 1 : 0;   // 1 => inputs are fp32
      *flag = sflag;
    }
  }
  __syncthreads();
  int isf32 = sflag;
  auto conv = [&](const void* src, float* dst, int n){
    for (int i = t; i < n; i += 256)
      dst[i] = isf32 ? ((const float*)src)[i] : bf2f(((const u16*)src)[i]);
  };
  conv(Wproj, cw + CW_WPROJ, 4096);
  conv(Wpos1, cw + CW_WPOS1, 1728);
  conv(Wpos2, cw + CW_WPOS2, 1728);
  conv(rescale, cw + CW_RESC, 4);
  conv(bproj,   cw + CW_BPROJ, 64);
}

// ---- pack [Wq|Wk|Wv] (64x192) into MFMA B-fragment order ----
__global__ __launch_bounds__(256) void kpack_w(const void* __restrict__ Wq,
                                               const void* __restrict__ Wk,
                                               const void* __restrict__ Wv,
                                               const int* __restrict__ flag,
                                               u16* __restrict__ packW){
  int isf32 = *flag;
  int o = blockIdx.x * 256 + threadIdx.x;      // 48*256 = 12288
  int f = o >> 9, l = (o >> 3) & 63, j = o & 7;
  int tt = f >> 1, s = f & 1;
  int k = s * 32 + (l >> 4) * 8 + j;
  int n = tt * 16 + (l & 15);
  const void* W = (n < 64) ? Wq : (n < 128) ? Wk : Wv;
  int idx = k * 64 + (n & 63);
  float val = isf32 ? ((const float*)W)[idx] : bf2f(((const u16*)W)[idx]);
  packW[o] = f2bf(val);
}

__device__ __forceinline__ short8 ld8_adapt(const void* p, size_t idx, int isf32){
  if (!isf32) return *(const short8*)((const u16*)p + idx);
  const float4* f = (const float4*)((const float*)p + idx);
  float4 u = f[0], v2 = f[1];
  short8 r;
  r[0] = (short)f2bf(u.x);  r[1] = (short)f2bf(u.y);
  r[2] = (short)f2bf(u.z);  r[3] = (short)f2bf(u.w);
  r[4] = (short)f2bf(v2.x); r[5] = (short)f2bf(v2.y);
  r[6] = (short)f2bf(v2.z); r[7] = (short)f2bf(v2.w);
  return r;
}

// ---- QKV GEMM + fused Gram/norms; writes only vT ----
__global__ __launch_bounds__(256) void k_qkv(const void* __restrict__ x, const int* __restrict__ flag,
                                             const u16* __restrict__ packW, u16* __restrict__ vT,
                                             float* __restrict__ Gp, float* __restrict__ NkP,
                                             float* __restrict__ NqP){
  __shared__ u16 sK[64][72];   // [ch][pt], pad 64->72 (2-way conflicts only)
  __shared__ u16 sQ[64][72];
  int isf32 = *flag;
  int wave = threadIdx.x >> 6, lane = threadIdx.x & 63;
  int m = lane & 15, quad = lane >> 4;
  int p0 = blockIdx.x * 64 + wave * 16;
  size_t rowbase = (size_t)(p0 + m) * 64;
  short8 a0 = ld8_adapt(x, rowbase + quad * 8, isf32);        // k = quad*8+j
  short8 a1 = ld8_adapt(x, rowbase + 32 + quad * 8, isf32);   // k = 32+quad*8+j
  const short8* bw = (const short8*)packW;
  f32x4 acc[12];
#pragma unroll
  for (int t = 0; t < 12; t++) acc[t] = (f32x4)(0.f);
#pragma unroll
  for (int t = 0; t < 12; t++){
    short8 b0 = bw[(t * 2 + 0) * 64 + lane];
    short8 b1 = bw[(t * 2 + 1) * 64 + lane];
    acc[t] = __builtin_amdgcn_mfma_f32_16x16x32_bf16(a0, b0, acc[t], 0, 0, 0);
    acc[t] = __builtin_amdgcn_mfma_f32_16x16x32_bf16(a1, b1, acc[t], 0, 0, 0);
  }
  int b = p0 >> 17;
  int nloc = p0 & (NPT - 1);
  int pl = wave * 16 + quad * 4;     // local point index within block
  // q tiles 0..3 -> sQ, k tiles 4..7 -> sK (bf16, [ch][pt])
#pragma unroll
  for (int t = 0; t < 4; t++){
    u16x4 pk;
#pragma unroll
    for (int r = 0; r < 4; r++) pk[r] = f2bf(acc[t][r]);
    *(u16x4*)&sQ[t * 16 + m][pl] = pk;
  }
#pragma unroll
  for (int t = 4; t < 8; t++){
    u16x4 pk;
#pragma unroll
    for (int r = 0; r < 4; r++) pk[r] = f2bf(acc[t][r]);
    *(u16x4*)&sK[(t - 4) * 16 + m][pl] = pk;
  }
  // v tiles 8..11 -> global vT [b][c][n]
#pragma unroll
  for (int t = 8; t < 12; t++){
    int ch = (t - 8) * 16 + m;
    u16x4 pk;
#pragma unroll
    for (int r = 0; r < 4; r++) pk[r] = f2bf(acc[t][r]);
    *(u16x4*)(vT + ((size_t)(b * 64 + ch)) * NPT + nloc + quad * 4) = pk;
  }
  __syncthreads();
  // wave w handles head h=w: G = K.Q^T, plus ||k||^2, ||q||^2 diagonals
  int h = wave;
  f32x4 aG = (f32x4)(0.f), aKK = (f32x4)(0.f), aQQ = (f32x4)(0.f);
#pragma unroll
  for (int cc = 0; cc < 2; cc++){
    short8 kf = *(const short8*)&sK[h * 16 + m][cc * 32 + quad * 8];
    short8 qf = *(const short8*)&sQ[h * 16 + m][cc * 32 + quad * 8];
    aG  = __builtin_amdgcn_mfma_f32_16x16x32_bf16(kf, qf, aG, 0, 0, 0);
    aKK = __builtin_amdgcn_mfma_f32_16x16x32_bf16(kf, kf, aKK, 0, 0, 0);
    aQQ = __builtin_amdgcn_mfma_f32_16x16x32_bf16(qf, qf, aQQ, 0, 0, 0);
  }
  int bk = blockIdx.x & (NBK - 1);
  float* Gb = Gp + ((size_t)(bk * 2 + b) * 4 + h) * 256;
#pragma unroll
  for (int r = 0; r < 4; r++){
    int d = quad * 4 + r, e = m;
    atomicAdd(&Gb[d * 16 + e], aG[r]);
    if (d == e){
      atomicAdd(&NkP[(bk * 2 + b) * 64 + h * 16 + d], aKK[r]);
      atomicAdd(&NqP[(bk * 2 + b) * 64 + h * 16 + d], aQQ[r]);
    }
  }
}

// ---- bucket-reduce + softmax + fold attn into Wproj, pack M ----
__global__ __launch_bounds__(256) void k_attn(const float* __restrict__ Gp, const float* __restrict__ NkP,
                                              const float* __restrict__ NqP, const float* __restrict__ cw,
                                              u16* __restrict__ packM){
  __shared__ float sG[1024];
  __shared__ float sNk[64], sNq[64];
  __shared__ float sA[4][16][16];
  __shared__ float sM[64][64];
  __shared__ float sWp[64][64];
  int b = blockIdx.x, t = threadIdx.x;
  for (int i = t; i < 1024; i += 256){
    float s = 0.f;
    for (int bk = 0; bk < NBK; bk++) s += Gp[(size_t)(bk * 2 + b) * 1024 + i];
    sG[i] = s;
  }
  if (t < 64){
    float s1 = 0.f, s2 = 0.f;
    for (int bk = 0; bk < NBK; bk++){
      s1 += NkP[(bk * 2 + b) * 64 + t];
      s2 += NqP[(bk * 2 + b) * 64 + t];
    }
    sNk[t] = s1; sNq[t] = s2;
  }
  for (int i = t; i < 4096; i += 256) sWp[i >> 6][i & 63] = cw[CW_WPROJ + i];
  __syncthreads();
  if (t < 64){
    int h = t >> 4, d = t & 15;
    float nk = fmaxf(sqrtf(sNk[t]), 1e-12f);
    float rs = cw[CW_RESC + h];
    float lg[16]; float mx = -1e30f;
#pragma unroll
    for (int e = 0; e < 16; e++){
      float nq = fmaxf(sqrtf(sNq[h * 16 + e]), 1e-12f);
      float L = sG[h * 256 + d * 16 + e] / (nk * nq) * rs;
      lg[e] = L; mx = fmaxf(mx, L);
    }
    float sum = 0.f;
#pragma unroll
    for (int e = 0; e < 16; e++){ lg[e] = expf(lg[e] - mx); sum += lg[e]; }
    float inv = 1.f / sum;
#pragma unroll
    for (int e = 0; e < 16; e++) sA[h][d][e] = lg[e] * inv;
  }
  __syncthreads();
  // M[he][c] = sum_d attn[h][d][e] * Wproj[h*16+d][c]
  for (int i = t; i < 4096; i += 256){
    int he = i >> 6, c = i & 63;
    int h = he >> 4, e = he & 15;
    float acc = 0.f;
#pragma unroll
    for (int d = 0; d < 16; d++) acc += sA[h][d][e] * sWp[h * 16 + d][c];
    sM[he][c] = acc;
  }
  __syncthreads();
  for (int i = t; i < 4096; i += 256){
    int f = i >> 9, l = (i >> 3) & 63, j = i & 7;
    int t4 = f >> 1, s = f & 1;
    int k = s * 32 + (l >> 4) * 8 + j;
    int n = t4 * 16 + (l & 15);
    packM[b * 4096 + i] = f2bf(sM[k][n]);
  }
}

// ---- depthwise 3x3x3 conv on channel-major planes, x-vectorized, y-pipelined ----
// thread = (c, 8-wide x strip); rolling 3-stage output accumulators.
template <bool GELU>
__global__ __launch_bounds__(256) void k_dwconv(const u16* __restrict__ src, const float* __restrict__ wpos,
                                                u16* __restrict__ dst){
  int xi = threadIdx.x & 15, cs = threadIdx.x >> 4;
  int x0 = xi * 8;
  int c  = blockIdx.x * 16 + cs;       // 4 ctiles
  int z  = blockIdx.y >> 4;            // 8
  int y0 = (blockIdx.y & 15) * 8;      // 16 y-tiles of 8
  int b  = blockIdx.z;                 // 2
  float wgt[27];
#pragma unroll
  for (int i = 0; i < 27; i++) wgt[i] = wpos[c * 27 + i];
  const u16* plane = src + (size_t)(b * 64 + c) * NPT;
  u16* oplane = dst + (size_t)(b * 64 + c) * NPT;
  float accA[8], accB[8], accC[8];
#pragma unroll
  for (int i = 0; i < 8; i++){ accA[i] = 0.f; accB[i] = 0.f; accC[i] = 0.f; }
#pragma unroll
  for (int s = 0; s < 10; s++){
    int yy = y0 - 1 + s;
    float row[3][10];
#pragma unroll
    for (int kd = 0; kd < 3; kd++){
      int zz = z - 1 + kd;
      if (zz >= 0 && zz < DD && yy >= 0 && yy < HH){
        const u16* rp = plane + zz * 16384 + yy * 128 + x0;
        short8 mid = *(const short8*)rp;
        u16 lft = 0, rgt = 0;
        if (x0 > 0)   lft = rp[-1];
        if (x0 < 120) rgt = rp[8];
        row[kd][0] = bf2f(lft);
#pragma unroll
        for (int e = 0; e < 8; e++) row[kd][1 + e] = bf2f((u16)mid[e]);
        row[kd][9] = bf2f(rgt);
      } else {
#pragma unroll
        for (int i = 0; i < 10; i++) row[kd][i] = 0.f;
      }
    }
    // row yy feeds: accA (out yy-1, kh=2), accB (out yy, kh=1), accC (out yy+1, kh=0)
#pragma unroll
    for (int kd = 0; kd < 3; kd++)
#pragma unroll
      for (int kw = 0; kw < 3; kw++){
        float w2 = wgt[kd * 9 + 6 + kw];
        float w1 = wgt[kd * 9 + 3 + kw];
        float w0 = wgt[kd * 9 + 0 + kw];
#pragma unroll
        for (int xx = 0; xx < 8; xx++){
          float v = row[kd][xx + kw];
          accA[xx] = fmaf(v, w2, accA[xx]);
          accB[xx] = fmaf(v, w1, accB[xx]);
          accC[xx] = fmaf(v, w0, accC[xx]);
        }
      }
    if (s >= 2){
      int ye = yy - 1;
      u16x8 pk;
#pragma unroll
      for (int xx = 0; xx < 8; xx++){
        float o = accA[xx];
        if (GELU) o = 0.5f * o * (1.f + erff(o * 0.70710678118654752f));
        pk[xx] = f2bf(o);
      }
      *(u16x8*)(oplane + z * 16384 + ye * 128 + x0) = pk;
    }
#pragma unroll
    for (int i = 0; i < 8; i++){ accA[i] = accB[i]; accB[i] = accC[i]; accC[i] = 0.f; }
  }
}

// ---- final: v @ M + bproj + conv2 output -> fp32 out ----
__global__ __launch_bounds__(256) void k_final(const u16* __restrict__ vT, const u16* __restrict__ packM,
                                               const float* __restrict__ bprojf, const u16* __restrict__ p2T,
                                               float* __restrict__ out){
  int wave = threadIdx.x >> 6, lane = threadIdx.x & 63;
  int m = lane & 15, quad = lane >> 4;
  int p0 = blockIdx.x * 64 + wave * 16;
  int b = p0 >> 17;
  int nloc = p0 & (NPT - 1);
  short8 a0, a1;
#pragma unroll
  for (int j = 0; j < 8; j++){
    a0[j] = (short)vT[(size_t)(b * 64 + quad * 8 + j) * NPT + nloc + m];
    a1[j] = (short)vT[(size_t)(b * 64 + 32 + quad * 8 + j) * NPT + nloc + m];
  }
  const short8* bm = (const short8*)(packM + (size_t)b * 4096);
  f32x4 acc[4];
#pragma unroll
  for (int t = 0; t < 4; t++) acc[t] = (f32x4)(0.f);
#pragma unroll
  for (int t = 0; t < 4; t++){
    short8 b0 = bm[(t * 2 + 0) * 64 + lane];
    short8 b1 = bm[(t * 2 + 1) * 64 + lane];
    acc[t] = __builtin_amdgcn_mfma_f32_16x16x32_bf16(a0, b0, acc[t], 0, 0, 0);
    acc[t] = __builtin_amdgcn_mfma_f32_16x16x32_bf16(a1, b1, acc[t], 0, 0, 0);
  }
#pragma unroll
  for (int t = 0; t < 4; t++){
    int c = t * 16 + m;
    float bias = bprojf[c];
    u16x4 pv = *(const u16x4*)(p2T + (size_t)(b * 64 + c) * NPT + nloc + quad * 4);
#pragma unroll
    for (int r = 0; r < 4; r++){
      size_t p = (size_t)p0 + quad * 4 + r;
      out[p * 64 + c] = acc[t][r] + bias + bf2f(pv[r]);
    }
  }
}

extern "C" void kernel_launch(void* const* d_in, const int* in_sizes, int n_in,
                              void* d_out, int out_size, void* d_ws, size_t ws_size,
                              hipStream_t stream){
  (void)in_sizes; (void)n_in; (void)out_size; (void)ws_size;
  const void* x      = d_in[0];
  const void* Wq     = d_in[1];
  const void* Wk     = d_in[2];
  const void* Wv     = d_in[3];
  const void* rescale= d_in[4];
  const void* Wproj  = d_in[5];
  const void* bproj  = d_in[6];
  const void* Wpos1  = d_in[7];
  const void* Wpos2  = d_in[8];

  char* ws = (char*)d_ws;
  u16* p1T   = (u16*)(ws + OFF_P1);
  u16* p2T   = (u16*)(ws + OFF_P2);
  u16* vT    = (u16*)(ws + OFF_V);
  u16* packW = (u16*)(ws + OFF_PW);
  u16* packM = (u16*)(ws + OFF_PM);
  int* flag  = (int*)(ws + OFF_FLAG);
  float* cw  = (float*)(ws + OFF_CW);
  float* Gp  = (float*)(ws + OFF_P1) + GP_F;    // partials alias p1 region
  float* NkP = (float*)(ws + OFF_P1) + NKP_F;
  float* NqP = (float*)(ws + OFF_P1) + NQP_F;
  float* out = (float*)d_out;

  k_prep<<<32, 256, 0, stream>>>(x, Wproj, rescale, bproj, Wpos1, Wpos2, flag, cw, Gp);
  kpack_w<<<48, 256, 0, stream>>>(Wq, Wk, Wv, flag, packW);
  k_qkv<<<NTOT / 64, 256, 0, stream>>>(x, flag, packW, vT, Gp, NkP, NqP);
  k_attn<<<2, 256, 0, stream>>>(Gp, NkP, NqP, cw, packM);
  k_dwconv<true><<<dim3(4, 128, 2), 256, 0, stream>>>(vT, cw + CW_WPOS1, p1T);
  k_dwconv<false><<<dim3(4, 128, 2), 256, 0, stream>>>(p1T, cw + CW_WPOS2, p2T);
  k_final<<<NTOT / 64, 256, 0, stream>>>(vT, packM, cw + CW_BPROJ, p2T, out);
}

// Round 6
// 304.404 us; speedup vs baseline: 2.3464x; 1.0766x over previous
//
#include <hip/hip_runtime.h>
#include <math.h>

#define DD 8
#define HH 128
#define WW2 128
#define NPT 131072
#define NTOT 262144
#define NBK 32

typedef __attribute__((ext_vector_type(8))) short short8;
typedef __attribute__((ext_vector_type(4))) float f32x4;
typedef __attribute__((ext_vector_type(4))) unsigned short u16x4;
typedef __attribute__((ext_vector_type(8))) unsigned short u16x8;
typedef unsigned short u16;

// ---- workspace layout (bytes) ----
static const size_t OFF_P1  = 0;          // bf16 p1T [b][64][NPT]
static const size_t OFF_P2  = 33554432;   // bf16 p2T [b][64][NPT]
static const size_t OFF_V   = 67108864;   // bf16 vT  [b][64][NPT]
static const size_t OFF_PW  = 100663296;  // 24576 packed W frags
static const size_t OFF_PM  = 100687872;  // 16384 packed M frags
static const size_t OFF_FLAG= 100704256;  // 4
static const size_t OFF_CW  = 100704768;  // canonical weights (fp32)
// float offsets inside the partial region (base = ws + OFF_P1):
#define GP_F    0        // [NBK][2][4][16][16] = 65536 floats
#define NKP_F   65536    // [NBK][2][64] = 4096 floats
#define NQP_F   69632    // [NBK][2][64] = 4096 floats
#define NPART_TOT 73728
// cw float offsets:
#define CW_WPROJ 0
#define CW_WPOS1 4096
#define CW_WPOS2 5824
#define CW_RESC  7552
#define CW_BPROJ 7556

__device__ __forceinline__ float bf2f(u16 u){
  unsigned int x = ((unsigned int)u) << 16;
  return __builtin_bit_cast(float, x);
}
__device__ __forceinline__ u16 f2bf(float f){
  unsigned int x = __builtin_bit_cast(unsigned int, f);
  unsigned int r = (x + 0x7fffu + ((x >> 16) & 1u)) >> 16;
  return (u16)r;
}

// ---- probe dtype, canonicalize small weights, zero partial buckets ----
__global__ __launch_bounds__(256) void k_prep(const void* __restrict__ x,
    const void* __restrict__ Wproj, const void* __restrict__ rescale,
    const void* __restrict__ bproj, const void* __restrict__ Wpos1,
    const void* __restrict__ Wpos2,
    int* __restrict__ flag, float* __restrict__ cw, float* __restrict__ gpart){
  __shared__ int sflag;
  int t = threadIdx.x, blk = blockIdx.x;
  for (int i = blk * 2304 + t; i < (blk + 1) * 2304 && i < NPART_TOT; i += 256)
    gpart[i] = 0.f;
  if (blk != 0) return;
  if (t < 64){
    u16 u = ((const u16*)x)[2 * t];
    int e = (u >> 7) & 0xFF;
    int plaus = (u == 0) || (u == 0x8000u) || (e >= 100 && e <= 130);
    unsigned long long m = __ballot(plaus);
    if (t == 0){
      sflag = (__popcll(m) < 48) ? 1 : 0;   // 1 => inputs are fp32
      *flag = sflag;
    }
  }
  __syncthreads();
  int isf32 = sflag;
  auto conv = [&](const void* src, float* dst, int n){
    for (int i = t; i < n; i += 256)
      dst[i] = isf32 ? ((const float*)src)[i] : bf2f(((const u16*)src)[i]);
  };
  conv(Wproj, cw + CW_WPROJ, 4096);
  conv(Wpos1, cw + CW_WPOS1, 1728);
  conv(Wpos2, cw + CW_WPOS2, 1728);
  conv(rescale, cw + CW_RESC, 4);
  conv(bproj,   cw + CW_BPROJ, 64);
}

// ---- pack [Wq|Wk|Wv] (64x192) into MFMA B-fragment order ----
__global__ __launch_bounds__(256) void kpack_w(const void* __restrict__ Wq,
                                               const void* __restrict__ Wk,
                                               const void* __restrict__ Wv,
                                               const int* __restrict__ flag,
                                               u16* __restrict__ packW){
  int isf32 = *flag;
  int o = blockIdx.x * 256 + threadIdx.x;      // 48*256 = 12288
  int f = o >> 9, l = (o >> 3) & 63, j = o & 7;
  int tt = f >> 1, s = f & 1;
  int k = s * 32 + (l >> 4) * 8 + j;
  int n = tt * 16 + (l & 15);
  const void* W = (n < 64) ? Wq : (n < 128) ? Wk : Wv;
  int idx = k * 64 + (n & 63);
  float val = isf32 ? ((const float*)W)[idx] : bf2f(((const u16*)W)[idx]);
  packW[o] = f2bf(val);
}

__device__ __forceinline__ short8 ld8_adapt(const void* p, size_t idx, int isf32){
  if (!isf32) return *(const short8*)((const u16*)p + idx);
  const float4* f = (const float4*)((const float*)p + idx);
  float4 u = f[0], v2 = f[1];
  short8 r;
  r[0] = (short)f2bf(u.x);  r[1] = (short)f2bf(u.y);
  r[2] = (short)f2bf(u.z);  r[3] = (short)f2bf(u.w);
  r[4] = (short)f2bf(v2.x); r[5] = (short)f2bf(v2.y);
  r[6] = (short)f2bf(v2.z); r[7] = (short)f2bf(v2.w);
  return r;
}

// ---- QKV GEMM + fused Gram/norms; writes only vT ----
__global__ __launch_bounds__(256) void k_qkv(const void* __restrict__ x, const int* __restrict__ flag,
                                             const u16* __restrict__ packW, u16* __restrict__ vT,
                                             float* __restrict__ Gp, float* __restrict__ NkP,
                                             float* __restrict__ NqP){
  __shared__ u16 sK[64][72];   // [ch][pt], pad 64->72 (2-way conflicts only)
  __shared__ u16 sQ[64][72];
  int isf32 = *flag;
  int wave = threadIdx.x >> 6, lane = threadIdx.x & 63;
  int m = lane & 15, quad = lane >> 4;
  int p0 = blockIdx.x * 64 + wave * 16;
  size_t rowbase = (size_t)(p0 + m) * 64;
  short8 a0 = ld8_adapt(x, rowbase + quad * 8, isf32);
  short8 a1 = ld8_adapt(x, rowbase + 32 + quad * 8, isf32);
  const short8* bw = (const short8*)packW;
  f32x4 acc[12];
#pragma unroll
  for (int t = 0; t < 12; t++) acc[t] = (f32x4)(0.f);
#pragma unroll
  for (int t = 0; t < 12; t++){
    short8 b0 = bw[(t * 2 + 0) * 64 + lane];
    short8 b1 = bw[(t * 2 + 1) * 64 + lane];
    acc[t] = __builtin_amdgcn_mfma_f32_16x16x32_bf16(a0, b0, acc[t], 0, 0, 0);
    acc[t] = __builtin_amdgcn_mfma_f32_16x16x32_bf16(a1, b1, acc[t], 0, 0, 0);
  }
  int b = p0 >> 17;
  int nloc = p0 & (NPT - 1);
  int pl = wave * 16 + quad * 4;
#pragma unroll
  for (int t = 0; t < 4; t++){
    u16x4 pk;
#pragma unroll
    for (int r = 0; r < 4; r++) pk[r] = f2bf(acc[t][r]);
    *(u16x4*)&sQ[t * 16 + m][pl] = pk;
  }
#pragma unroll
  for (int t = 4; t < 8; t++){
    u16x4 pk;
#pragma unroll
    for (int r = 0; r < 4; r++) pk[r] = f2bf(acc[t][r]);
    *(u16x4*)&sK[(t - 4) * 16 + m][pl] = pk;
  }
#pragma unroll
  for (int t = 8; t < 12; t++){
    int ch = (t - 8) * 16 + m;
    u16x4 pk;
#pragma unroll
    for (int r = 0; r < 4; r++) pk[r] = f2bf(acc[t][r]);
    *(u16x4*)(vT + ((size_t)(b * 64 + ch)) * NPT + nloc + quad * 4) = pk;
  }
  __syncthreads();
  int h = wave;
  f32x4 aG = (f32x4)(0.f), aKK = (f32x4)(0.f), aQQ = (f32x4)(0.f);
#pragma unroll
  for (int cc = 0; cc < 2; cc++){
    short8 kf = *(const short8*)&sK[h * 16 + m][cc * 32 + quad * 8];
    short8 qf = *(const short8*)&sQ[h * 16 + m][cc * 32 + quad * 8];
    aG  = __builtin_amdgcn_mfma_f32_16x16x32_bf16(kf, qf, aG, 0, 0, 0);
    aKK = __builtin_amdgcn_mfma_f32_16x16x32_bf16(kf, kf, aKK, 0, 0, 0);
    aQQ = __builtin_amdgcn_mfma_f32_16x16x32_bf16(qf, qf, aQQ, 0, 0, 0);
  }
  int bk = blockIdx.x & (NBK - 1);
  float* Gb = Gp + ((size_t)(bk * 2 + b) * 4 + h) * 256;
#pragma unroll
  for (int r = 0; r < 4; r++){
    int d = quad * 4 + r, e = m;
    atomicAdd(&Gb[d * 16 + e], aG[r]);
    if (d == e){
      atomicAdd(&NkP[(bk * 2 + b) * 64 + h * 16 + d], aKK[r]);
      atomicAdd(&NqP[(bk * 2 + b) * 64 + h * 16 + d], aQQ[r]);
    }
  }
}

// ---- bucket-reduce + softmax + fold attn into Wproj, pack M ----
__global__ __launch_bounds__(256) void k_attn(const float* __restrict__ Gp, const float* __restrict__ NkP,
                                              const float* __restrict__ NqP, const float* __restrict__ cw,
                                              u16* __restrict__ packM){
  __shared__ float sG[1024];
  __shared__ float sNk[64], sNq[64];
  __shared__ float sA[4][16][16];
  __shared__ float sM[64][64];
  __shared__ float sWp[64][64];
  int b = blockIdx.x, t = threadIdx.x;
  for (int i = t; i < 1024; i += 256){
    float s = 0.f;
    for (int bk = 0; bk < NBK; bk++) s += Gp[(size_t)(bk * 2 + b) * 1024 + i];
    sG[i] = s;
  }
  if (t < 64){
    float s1 = 0.f, s2 = 0.f;
    for (int bk = 0; bk < NBK; bk++){
      s1 += NkP[(bk * 2 + b) * 64 + t];
      s2 += NqP[(bk * 2 + b) * 64 + t];
    }
    sNk[t] = s1; sNq[t] = s2;
  }
  for (int i = t; i < 4096; i += 256) sWp[i >> 6][i & 63] = cw[CW_WPROJ + i];
  __syncthreads();
  if (t < 64){
    int h = t >> 4, d = t & 15;
    float nk = fmaxf(sqrtf(sNk[t]), 1e-12f);
    float rs = cw[CW_RESC + h];
    float lg[16]; float mx = -1e30f;
#pragma unroll
    for (int e = 0; e < 16; e++){
      float nq = fmaxf(sqrtf(sNq[h * 16 + e]), 1e-12f);
      float L = sG[h * 256 + d * 16 + e] / (nk * nq) * rs;
      lg[e] = L; mx = fmaxf(mx, L);
    }
    float sum = 0.f;
#pragma unroll
    for (int e = 0; e < 16; e++){ lg[e] = expf(lg[e] - mx); sum += lg[e]; }
    float inv = 1.f / sum;
#pragma unroll
    for (int e = 0; e < 16; e++) sA[h][d][e] = lg[e] * inv;
  }
  __syncthreads();
  for (int i = t; i < 4096; i += 256){
    int he = i >> 6, c = i & 63;
    int h = he >> 4, e = he & 15;
    float acc = 0.f;
#pragma unroll
    for (int d = 0; d < 16; d++) acc += sA[h][d][e] * sWp[h * 16 + d][c];
    sM[he][c] = acc;
  }
  __syncthreads();
  for (int i = t; i < 4096; i += 256){
    int f = i >> 9, l = (i >> 3) & 63, j = i & 7;
    int t4 = f >> 1, s = f & 1;
    int k = s * 32 + (l >> 4) * 8 + j;
    int n = t4 * 16 + (l & 15);
    packM[b * 4096 + i] = f2bf(sM[k][n]);
  }
}

// ---- depthwise 3x3x3 conv: thread = 8-wide x strip at one (c,z,y) ----
// 8192 blocks (occupancy-first); unconditional clamped row loads (9 independent
// 16B VMEM ops, hoistable); row validity folded into weights (no divergence).
template <bool GELU>
__global__ __launch_bounds__(256) void k_dwconv(const u16* __restrict__ src, const float* __restrict__ wpos,
                                                u16* __restrict__ dst){
  int xi = threadIdx.x & 15, ty = threadIdx.x >> 4;
  int x0 = xi * 8;
  int c  = blockIdx.x;                  // 64 (uniform -> wgt in SGPRs)
  int z  = blockIdx.y >> 3;             // 8
  int y  = (blockIdx.y & 7) * 16 + ty;  // 128
  int b  = blockIdx.z;                  // 2
  float wgt[27];
#pragma unroll
  for (int i = 0; i < 27; i++) wgt[i] = wpos[c * 27 + i];
  const u16* plane = src + (size_t)(b * 64 + c) * NPT;
  float acc[8];
#pragma unroll
  for (int i = 0; i < 8; i++) acc[i] = 0.f;
#pragma unroll
  for (int kd = 0; kd < 3; kd++){
    int zz = z - 1 + kd;
    if (zz < 0 || zz >= DD) continue;          // wave-uniform branch
#pragma unroll
    for (int kh = 0; kh < 3; kh++){
      int yyr = y - 1 + kh;
      int yc = yyr < 0 ? 0 : (yyr > HH - 1 ? HH - 1 : yyr);   // clamped addr
      float vmask = (yyr == yc) ? 1.f : 0.f;                  // validity
      const u16* rp = plane + zz * 16384 + yc * 128 + x0;
      short8 mid = *(const short8*)rp;
      u16 lft = 0, rgt = 0;
      if (x0 > 0)   lft = rp[-1];
      if (x0 < 120) rgt = rp[8];
      float row[10];
      row[0] = bf2f(lft);
#pragma unroll
      for (int e = 0; e < 8; e++) row[1 + e] = bf2f((u16)mid[e]);
      row[9] = bf2f(rgt);
#pragma unroll
      for (int kw = 0; kw < 3; kw++){
        float w = wgt[kd * 9 + kh * 3 + kw] * vmask;
#pragma unroll
        for (int xx = 0; xx < 8; xx++)
          acc[xx] = fmaf(row[xx + kw], w, acc[xx]);
      }
    }
  }
  u16x8 pk;
#pragma unroll
  for (int xx = 0; xx < 8; xx++){
    float o = acc[xx];
    if (GELU) o = 0.5f * o * (1.f + erff(o * 0.70710678118654752f));
    pk[xx] = f2bf(o);
  }
  *(u16x8*)(dst + (size_t)(b * 64 + c) * NPT + z * 16384 + y * 128 + x0) = pk;
}

// ---- final: v @ M + bproj + conv2 output -> fp32 out ----
__global__ __launch_bounds__(256) void k_final(const u16* __restrict__ vT, const u16* __restrict__ packM,
                                               const float* __restrict__ bprojf, const u16* __restrict__ p2T,
                                               float* __restrict__ out){
  int wave = threadIdx.x >> 6, lane = threadIdx.x & 63;
  int m = lane & 15, quad = lane >> 4;
  int p0 = blockIdx.x * 64 + wave * 16;
  int b = p0 >> 17;
  int nloc = p0 & (NPT - 1);
  short8 a0, a1;
#pragma unroll
  for (int j = 0; j < 8; j++){
    a0[j] = (short)vT[(size_t)(b * 64 + quad * 8 + j) * NPT + nloc + m];
    a1[j] = (short)vT[(size_t)(b * 64 + 32 + quad * 8 + j) * NPT + nloc + m];
  }
  const short8* bm = (const short8*)(packM + (size_t)b * 4096);
  f32x4 acc[4];
#pragma unroll
  for (int t = 0; t < 4; t++) acc[t] = (f32x4)(0.f);
#pragma unroll
  for (int t = 0; t < 4; t++){
    short8 b0 = bm[(t * 2 + 0) * 64 + lane];
    short8 b1 = bm[(t * 2 + 1) * 64 + lane];
    acc[t] = __builtin_amdgcn_mfma_f32_16x16x32_bf16(a0, b0, acc[t], 0, 0, 0);
    acc[t] = __builtin_amdgcn_mfma_f32_16x16x32_bf16(a1, b1, acc[t], 0, 0, 0);
  }
#pragma unroll
  for (int t = 0; t < 4; t++){
    int c = t * 16 + m;
    float bias = bprojf[c];
    u16x4 pv = *(const u16x4*)(p2T + (size_t)(b * 64 + c) * NPT + nloc + quad * 4);
#pragma unroll
    for (int r = 0; r < 4; r++){
      size_t p = (size_t)p0 + quad * 4 + r;
      out[p * 64 + c] = acc[t][r] + bias + bf2f(pv[r]);
    }
  }
}

extern "C" void kernel_launch(void* const* d_in, const int* in_sizes, int n_in,
                              void* d_out, int out_size, void* d_ws, size_t ws_size,
                              hipStream_t stream){
  (void)in_sizes; (void)n_in; (void)out_size; (void)ws_size;
  const void* x      = d_in[0];
  const void* Wq     = d_in[1];
  const void* Wk     = d_in[2];
  const void* Wv     = d_in[3];
  const void* rescale= d_in[4];
  const void* Wproj  = d_in[5];
  const void* bproj  = d_in[6];
  const void* Wpos1  = d_in[7];
  const void* Wpos2  = d_in[8];

  char* ws = (char*)d_ws;
  u16* p1T   = (u16*)(ws + OFF_P1);
  u16* p2T   = (u16*)(ws + OFF_P2);
  u16* vT    = (u16*)(ws + OFF_V);
  u16* packW = (u16*)(ws + OFF_PW);
  u16* packM = (u16*)(ws + OFF_PM);
  int* flag  = (int*)(ws + OFF_FLAG);
  float* cw  = (float*)(ws + OFF_CW);
  float* Gp  = (float*)(ws + OFF_P1) + GP_F;
  float* NkP = (float*)(ws + OFF_P1) + NKP_F;
  float* NqP = (float*)(ws + OFF_P1) + NQP_F;
  float* out = (float*)d_out;

  k_prep<<<32, 256, 0, stream>>>(x, Wproj, rescale, bproj, Wpos1, Wpos2, flag, cw, Gp);
  kpack_w<<<48, 256, 0, stream>>>(Wq, Wk, Wv, flag, packW);
  k_qkv<<<NTOT / 64, 256, 0, stream>>>(x, flag, packW, vT, Gp, NkP, NqP);
  k_attn<<<2, 256, 0, stream>>>(Gp, NkP, NqP, cw, packM);
  k_dwconv<true><<<dim3(64, 64, 2), 256, 0, stream>>>(vT, cw + CW_WPOS1, p1T);
  k_dwconv<false><<<dim3(64, 64, 2), 256, 0, stream>>>(p1T, cw + CW_WPOS2, p2T);
  k_final<<<NTOT / 64, 256, 0, stream>>>(vT, packM, cw + CW_BPROJ, p2T, out);
}